// Round 4
// baseline (203.645 us; speedup 1.0000x reference)
//
#include <hip/hip_runtime.h>
#include <math.h>
#include <stdint.h>

#define PI2 6.28318530717958647692f

typedef __bf16 bf16x8 __attribute__((ext_vector_type(8)));
typedef float f32x4 __attribute__((ext_vector_type(4)));

typedef __attribute__((address_space(1))) const void gvoid_t;
typedef __attribute__((address_space(3))) void lvoid_t;

__device__ __forceinline__ void g2l16(const void* g, void* l) {
    __builtin_amdgcn_global_load_lds(
        reinterpret_cast<gvoid_t*>(reinterpret_cast<uintptr_t>(g)),
        reinterpret_cast<lvoid_t*>(reinterpret_cast<uintptr_t>(l)),
        16, 0, 0);
}

__device__ __forceinline__ short f2bf(float f) {
    unsigned u = __float_as_uint(f);
    u += 0x7FFFu + ((u >> 16) & 1u);          // round-to-nearest-even
    return (short)(u >> 16);
}

__device__ __forceinline__ unsigned pack2bf(float a, float b) {
    return (unsigned)(unsigned short)f2bf(a) |
           ((unsigned)(unsigned short)f2bf(b) << 16);
}

__device__ __forceinline__ float bflo(unsigned v) { return __uint_as_float(v << 16); }
__device__ __forceinline__ float bfhi(unsigned v) { return __uint_as_float(v & 0xFFFF0000u); }

// XCD-locality swizzle (G must be a multiple of 8 -> bijective).
__device__ __forceinline__ int xcd_swizzle(int blk, int G) {
    return (blk & 7) * (G >> 3) + (blk >> 3);
}

// ---------------------------------------------------------------------------
// aux1: x-side prep + out zero-init. 4096 blocks.
//   blocks [0,1024):    xe/xo radix-2 fold of x (1024x2048 each, bf16)
//   blocks [1024,3072): B1f folded DFT basis (2048x2048)
//   blocks [3072,4096): zero out (1024x4096 f32) for g4's atomic epilogue
// ---------------------------------------------------------------------------
__global__ __launch_bounds__(256) void aux1(
    const float* __restrict__ x,
    short* __restrict__ xe, short* __restrict__ xo,
    short* __restrict__ B1f, float* __restrict__ outz)
{
    int b = blockIdx.x;
    if (b < 1024) {
        unsigned i = (b * 256u + threadIdx.x) * 8u;
        int r = i >> 11, j0 = i & 2047;
        const float* xr = x + (size_t)r * 4096 + j0;
        float4 a0 = ((const float4*)xr)[0], a1 = ((const float4*)xr)[1];
        float4 b0 = ((const float4*)(xr + 2048))[0],
               b1 = ((const float4*)(xr + 2048))[1];
        uint4 oe = {pack2bf(a0.x + b0.x, a0.y + b0.y),
                    pack2bf(a0.z + b0.z, a0.w + b0.w),
                    pack2bf(a1.x + b1.x, a1.y + b1.y),
                    pack2bf(a1.z + b1.z, a1.w + b1.w)};
        *(uint4*)(xe + i) = oe;
        uint4 oo = {pack2bf(a0.x - b0.x, a0.y - b0.y),
                    pack2bf(a0.z - b0.z, a0.w - b0.w),
                    pack2bf(a1.x - b1.x, a1.y - b1.y),
                    pack2bf(a1.z - b1.z, a1.w - b1.w)};
        *(uint4*)(xo + i) = oo;
    } else if (b < 3072) {
        unsigned i = ((b - 1024) * 256u + threadIdx.x) * 8u;
        int r = i >> 11, j0 = i & 2047;
        const float inv_n = 1.0f / 4096.0f;
        float v[8];
        if (r < 512) {
            if (r == 0) {
                #pragma unroll
                for (int u = 0; u < 8; ++u) v[u] = inv_n;
            } else {
                #pragma unroll
                for (int u = 0; u < 8; ++u) {
                    int t = (r * (j0 + u)) & 2047;
                    v[u] = 2.0f * inv_n * cosf((float)t * (PI2 / 2048.0f));
                }
            }
        } else if (r < 1024) {
            int m = r - 512;
            #pragma unroll
            for (int u = 0; u < 8; ++u) {
                int t = (m * (j0 + u)) & 2047;
                v[u] = -2.0f * inv_n * sinf((float)t * (PI2 / 2048.0f));
            }
        } else if (r < 1536) {
            int c = 2 * (r - 1024) + 1;
            #pragma unroll
            for (int u = 0; u < 8; ++u) {
                int t = (c * (j0 + u)) & 4095;
                v[u] = 2.0f * inv_n * cosf((float)t * (PI2 / 4096.0f));
            }
        } else {
            int m = 2 * (r - 1536) + 1;
            #pragma unroll
            for (int u = 0; u < 8; ++u) {
                int t = (m * (j0 + u)) & 4095;
                v[u] = -2.0f * inv_n * sinf((float)t * (PI2 / 4096.0f));
            }
        }
        uint4 o = {pack2bf(v[0], v[1]), pack2bf(v[2], v[3]),
                   pack2bf(v[4], v[5]), pack2bf(v[6], v[7])};
        *(uint4*)(B1f + i) = o;
    } else {
        // zero out: 1024 blocks x 256 thr x 16 floats = 4,194,304 floats
        size_t idx = ((size_t)(b - 3072) * 256 + threadIdx.x) * 16;
        uint4 zz = {0, 0, 0, 0};
        *(uint4*)(outz + idx)     = zz;
        *(uint4*)(outz + idx + 8) = zz;
    }
}

// ---------------------------------------------------------------------------
// aux2 body: weight-side prep (independent of g1's inputs).
//   b2 [0,2048):    Vcat2 (2048x2048), cols permuted to B1f channel order
//   b2 [2048,3072): B2 (1024x2048), B2[p][k] = basis_p(k) * S[k]
//   b2 [3072,5120): Ucat (4096x1024) = [Ur | Ui]
// ---------------------------------------------------------------------------
__device__ __forceinline__ void aux2_body(
    int b2,
    const float* __restrict__ Ur, const float* __restrict__ Ui,
    const float* __restrict__ S,
    const float* __restrict__ Vr, const float* __restrict__ Vi,
    short* __restrict__ Vcat, short* __restrict__ B2,
    short* __restrict__ Ucat)
{
    if (b2 < 2048) {
        unsigned i = (b2 * 256u + threadIdx.x) * 8u;
        int k = i >> 11, c0 = i & 2047;
        int cls = c0 >> 9, cc0 = c0 & 511;
        const float* src = ((cls & 1) ? Vi : Vr) + (size_t)k * 1024 + 2 * cc0;
        float4 q0 = ((const float4*)src)[0];
        float4 q1 = ((const float4*)src)[1];
        float4 q2 = ((const float4*)src)[2];
        float4 q3 = ((const float4*)src)[3];
        float v[8];
        if ((cls >> 1) == 0) {
            v[0] = q0.x; v[1] = q0.z; v[2] = q1.x; v[3] = q1.z;
            v[4] = q2.x; v[5] = q2.z; v[6] = q3.x; v[7] = q3.z;
        } else {
            v[0] = q0.y; v[1] = q0.w; v[2] = q1.y; v[3] = q1.w;
            v[4] = q2.y; v[5] = q2.w; v[6] = q3.y; v[7] = q3.w;
        }
        uint4 o = {pack2bf(v[0], v[1]), pack2bf(v[2], v[3]),
                   pack2bf(v[4], v[5]), pack2bf(v[6], v[7])};
        *(uint4*)(Vcat + i) = o;
    } else if (b2 < 3072) {
        unsigned i = ((b2 - 2048) * 256u + threadIdx.x) * 8u;
        int p = i >> 11, k0 = i & 2047;
        float4 s0 = *(const float4*)(S + k0);
        float4 s1 = *(const float4*)(S + k0 + 4);
        float sv[8] = {s0.x, s0.y, s0.z, s0.w, s1.x, s1.y, s1.z, s1.w};
        const float inv_n = 1.0f / 2048.0f;
        float v[8];
        if (p == 0) {
            #pragma unroll
            for (int u = 0; u < 8; ++u) v[u] = inv_n * sv[u];
        } else if (p < 512) {
            #pragma unroll
            for (int u = 0; u < 8; ++u) {
                int t = (p * (k0 + u)) & 2047;
                v[u] = 2.0f * inv_n * cosf((float)t * (PI2 / 2048.0f)) * sv[u];
            }
        } else {
            int q = p - 512;
            #pragma unroll
            for (int u = 0; u < 8; ++u) {
                int t = (q * (k0 + u)) & 2047;
                v[u] = -2.0f * inv_n * sinf((float)t * (PI2 / 2048.0f)) * sv[u];
            }
        }
        uint4 o = {pack2bf(v[0], v[1]), pack2bf(v[2], v[3]),
                   pack2bf(v[4], v[5]), pack2bf(v[6], v[7])};
        *(uint4*)(B2 + i) = o;
    } else {
        unsigned i = ((b2 - 3072) * 256u + threadIdx.x) * 8u;
        int o_ = i >> 10, c = i & 1023;
        const float* src = (c < 512) ? (Ur + (size_t)o_ * 512 + c)
                                     : (Ui + (size_t)o_ * 512 + (c - 512));
        float4 a = ((const float4*)src)[0], b = ((const float4*)src)[1];
        uint4 o = {pack2bf(a.x, a.y), pack2bf(a.z, a.w),
                   pack2bf(b.x, b.y), pack2bf(b.z, b.w)};
        *(uint4*)(Ucat + i) = o;
    }
}

// Standalone aux2 for the small-ws fallback path.
__global__ __launch_bounds__(256) void aux2_only(
    const float* __restrict__ Ur, const float* __restrict__ Ui,
    const float* __restrict__ S,
    const float* __restrict__ Vr, const float* __restrict__ Vi,
    short* __restrict__ Vcat, short* __restrict__ B2,
    short* __restrict__ Ucat)
{
    aux2_body((int)blockIdx.x, Ur, Ui, S, Vr, Vi, Vcat, B2, Ucat);
}

// ---------------------------------------------------------------------------
// Shared 128x128 MFMA tile core, BK=64, XOR-swizzled LDS (round-4 proven).
// ---------------------------------------------------------------------------
__device__ __forceinline__ void tile_core(
    const short* __restrict__ A, int lda,
    const short* __restrict__ B, int ldb, int K,
    short* As, short* Bs, int bm, int bn, f32x4 (&acc)[4][4])
{
    const int tid  = threadIdx.x;
    const int wave = tid >> 6;
    const int lane = tid & 63;
    const int wm   = (wave >> 1) << 6;
    const int wn   = (wave & 1) << 6;
    const int l16  = lane & 15;
    const int quad = lane >> 4;
    const int rk   = l16 & 7;

    int aoff[4], boff[4], loff[4];
    #pragma unroll
    for (int p = 0; p < 4; ++p) {
        int L   = p * 256 + wave * 64 + lane;
        int row = L >> 3;
        int swz = (L & 7) ^ (row & 7);
        aoff[p] = (bm + row) * lda + swz * 8;
        boff[p] = (bn + row) * ldb + swz * 8;
        loff[p] = L * 8;
    }

    for (int k0 = 0; k0 < K; k0 += 64) {
        __syncthreads();
        #pragma unroll
        for (int p = 0; p < 4; ++p) g2l16(A + aoff[p] + k0, As + loff[p]);
        #pragma unroll
        for (int p = 0; p < 4; ++p) g2l16(B + boff[p] + k0, Bs + loff[p]);
        __syncthreads();

        #pragma unroll
        for (int h = 0; h < 2; ++h) {
            const int cs8 = ((((h << 2) | quad) ^ rk) << 3);
            bf16x8 b[4];
            #pragma unroll
            for (int nt = 0; nt < 4; ++nt)
                b[nt] = *(const bf16x8*)(Bs + (wn + nt * 16 + l16) * 64 + cs8);
            #pragma unroll
            for (int mt = 0; mt < 4; ++mt) {
                bf16x8 a = *(const bf16x8*)(As + (wm + mt * 16 + l16) * 64 + cs8);
                #pragma unroll
                for (int nt = 0; nt < 4; ++nt)
                    acc[mt][nt] = __builtin_amdgcn_mfma_f32_16x16x32_bf16(
                        a, b[nt], acc[mt][nt], 0, 0, 0);
            }
        }
    }
}

__device__ __forceinline__ void store_tile_bf16(
    f32x4 (&acc)[4][4], short* __restrict__ C, int ldc, int bm, int bn)
{
    const int tid  = threadIdx.x;
    const int wave = tid >> 6;
    const int lane = tid & 63;
    const int wm   = (wave >> 1) << 6;
    const int wn   = (wave & 1) << 6;
    const int l16  = lane & 15;
    const int quad = lane >> 4;
    #pragma unroll
    for (int nt = 0; nt < 4; ++nt) {
        int col = bn + wn + nt * 16 + l16;
        #pragma unroll
        for (int mt = 0; mt < 4; ++mt) {
            int rowb = bm + wm + mt * 16 + quad * 4;
            #pragma unroll
            for (int r = 0; r < 4; ++r)
                C[(size_t)(rowb + r) * ldc + col] = f2bf(acc[mt][nt][r]);
        }
    }
}

// Fragment-layout store: 8 coalesced uint4 per thread (round-7 proven).
__device__ __forceinline__ void store_frag(
    f32x4 (&acc)[4][4], short* __restrict__ planeTile)
{
    uint4* p = (uint4*)planeTile;
    const int tid = threadIdx.x;
    #pragma unroll
    for (int c = 0; c < 8; ++c) {
        int nt = c >> 1, mt0 = (c & 1) * 2;
        uint4 o = {pack2bf(acc[mt0][nt][0],     acc[mt0][nt][1]),
                   pack2bf(acc[mt0][nt][2],     acc[mt0][nt][3]),
                   pack2bf(acc[mt0 + 1][nt][0], acc[mt0 + 1][nt][1]),
                   pack2bf(acc[mt0 + 1][nt][2], acc[mt0 + 1][nt][3])};
        p[c * 256 + tid] = o;
    }
}

// Reduce one fragment chunk (tile, c) across SK planes -> row-major output.
template <bool OUT_F32>
__device__ __forceinline__ void reduce_unit(
    const short* __restrict__ P, size_t planeU4, int SK,
    int tile, int c, int tilesX, void* __restrict__ Out, int ldc,
    const float* __restrict__ bias)
{
    const int bm = (tile / tilesX) << 7;
    const int bn = (tile % tilesX) << 7;
    const int tid  = threadIdx.x;
    const int wave = tid >> 6;
    const int lane = tid & 63;
    const int wm   = (wave >> 1) << 6;
    const int wn   = (wave & 1) << 6;
    const int l16  = lane & 15;
    const int quad = lane >> 4;
    const int nt   = c >> 1, mt0 = (c & 1) * 2;

    const uint4* P4 = (const uint4*)P;
    const size_t base = (size_t)tile * 2048 + (size_t)c * 256 + tid;
    float f[8] = {0, 0, 0, 0, 0, 0, 0, 0};
    for (int z = 0; z < SK; ++z) {
        uint4 v = P4[(size_t)z * planeU4 + base];
        f[0] += bflo(v.x); f[1] += bfhi(v.x);
        f[2] += bflo(v.y); f[3] += bfhi(v.y);
        f[4] += bflo(v.z); f[5] += bfhi(v.z);
        f[6] += bflo(v.w); f[7] += bfhi(v.w);
    }
    const int col = bn + wn + nt * 16 + l16;
    float bv = 0.f;
    if (OUT_F32) bv = bias[col];
    #pragma unroll
    for (int j = 0; j < 8; ++j) {
        int mt  = mt0 + (j >> 2);
        int row = bm + wm + mt * 16 + quad * 4 + (j & 3);
        if (OUT_F32)
            ((float*)Out)[(size_t)row * ldc + col] = f[j] + bv;
        else
            ((short*)Out)[(size_t)row * ldc + col] = f2bf(f[j]);
    }
}

// ---------------------------------------------------------------------------
// g1 merged with aux2: blocks [0,512) do the folded stage-1 split-K GEMM
// (SK=4, Kpart=512), blocks [512, 5632) generate Vcat/B2/Ucat concurrently.
// ---------------------------------------------------------------------------
__global__ __launch_bounds__(256, 4) void gemm_s1f_aux(
    const short* __restrict__ xe, const short* __restrict__ xo,
    const short* __restrict__ B1f, short* __restrict__ P,
    const float* __restrict__ Ur, const float* __restrict__ Ui,
    const float* __restrict__ S,
    const float* __restrict__ Vr, const float* __restrict__ Vi,
    short* __restrict__ Vcat, short* __restrict__ B2,
    short* __restrict__ Ucat)
{
    if (blockIdx.x >= 512) {
        aux2_body((int)blockIdx.x - 512, Ur, Ui, S, Vr, Vi, Vcat, B2, Ucat);
        return;
    }

    __shared__ __align__(16) short As[128 * 64];
    __shared__ __align__(16) short Bs[128 * 64];

    f32x4 acc[4][4];
    #pragma unroll
    for (int i = 0; i < 4; ++i)
        #pragma unroll
        for (int j = 0; j < 4; ++j)
            acc[i][j] = (f32x4){0.f, 0.f, 0.f, 0.f};

    const int u    = xcd_swizzle((int)blockIdx.x, 512);
    const int z    = u >> 7;          // SK = 4
    const int tile = u & 127;         // 8 x 16 tiles
    const int tx   = tile & 15, ty = tile >> 4;
    const bool odd = (tx & 8) != 0;
    const short* A = (odd ? xo : xe) + (size_t)z * 512;
    const short* B = B1f + (odd ? (size_t)1024 * 2048 : 0) + (size_t)z * 512;
    const int bm   = ty << 7;
    const int bn   = (tx & 7) << 7;

    tile_core(A, 2048, B, 2048, 512, As, Bs, bm, bn, acc);
    store_frag(acc, P + (size_t)z * 2097152 + (size_t)tile * 16384);
}

// ---------------------------------------------------------------------------
// Split-K GEMM into fragment-layout bf16 partial planes, 1-D grid,
// XCD-swizzled. tileShift: log2(tiles per plane); tilesXShift: log2(tilesX).
// ---------------------------------------------------------------------------
__global__ __launch_bounds__(256, 4) void gemm_sk_frag(
    const short* __restrict__ A, int lda,
    const short* __restrict__ B, int ldb,
    short* __restrict__ P, size_t planeShorts, int Kpart,
    int tileShift, int tilesXShift)
{
    __shared__ __align__(16) short As[128 * 64];
    __shared__ __align__(16) short Bs[128 * 64];

    f32x4 acc[4][4];
    #pragma unroll
    for (int i = 0; i < 4; ++i)
        #pragma unroll
        for (int j = 0; j < 4; ++j)
            acc[i][j] = (f32x4){0.f, 0.f, 0.f, 0.f};

    const int u    = xcd_swizzle((int)blockIdx.x, (int)gridDim.x);
    const int z    = u >> tileShift;
    const int tile = u & ((1 << tileShift) - 1);
    const int bm   = (tile >> tilesXShift) << 7;
    const int bn   = (tile & ((1 << tilesXShift) - 1)) << 7;

    tile_core(A + (size_t)z * Kpart, lda, B + (size_t)z * Kpart, ldb, Kpart,
              As, Bs, bm, bn, acc);
    store_frag(acc, P + (size_t)z * planeShorts + (size_t)tile * 16384);
}

template <bool OUT_F32>
__global__ __launch_bounds__(256) void reduce_frag(
    const short* __restrict__ P, size_t planeShorts, int SK,
    int tilesX, void* __restrict__ Out, int ldc,
    const float* __restrict__ bias)
{
    reduce_unit<OUT_F32>(P, planeShorts >> 3, SK,
                         (int)(blockIdx.x >> 3), (int)(blockIdx.x & 7),
                         tilesX, Out, ldc, bias);
}

// ---------------------------------------------------------------------------
// Final GEMM with f32 atomicAdd split-K epilogue (out zero-init'd in aux1).
// z==0 blocks add bias. SK = gridDim/tiles.
// ---------------------------------------------------------------------------
__global__ __launch_bounds__(256, 4) void gemm_sk_atomic(
    const short* __restrict__ A, int lda,
    const short* __restrict__ B, int ldb, int Kpart,
    int tileShift, int tilesXShift,
    float* __restrict__ Out, int ldc, const float* __restrict__ bias)
{
    __shared__ __align__(16) short As[128 * 64];
    __shared__ __align__(16) short Bs[128 * 64];

    f32x4 acc[4][4];
    #pragma unroll
    for (int i = 0; i < 4; ++i)
        #pragma unroll
        for (int j = 0; j < 4; ++j)
            acc[i][j] = (f32x4){0.f, 0.f, 0.f, 0.f};

    const int u    = xcd_swizzle((int)blockIdx.x, (int)gridDim.x);
    const int z    = u >> tileShift;
    const int tile = u & ((1 << tileShift) - 1);
    const int bm   = (tile >> tilesXShift) << 7;
    const int bn   = (tile & ((1 << tilesXShift) - 1)) << 7;

    tile_core(A + (size_t)z * Kpart, lda, B + (size_t)z * Kpart, ldb, Kpart,
              As, Bs, bm, bn, acc);

    const int tid  = threadIdx.x;
    const int wave = tid >> 6;
    const int lane = tid & 63;
    const int wm   = (wave >> 1) << 6;
    const int wn   = (wave & 1) << 6;
    const int l16  = lane & 15;
    const int quad = lane >> 4;

    #pragma unroll
    for (int nt = 0; nt < 4; ++nt) {
        int col = bn + wn + nt * 16 + l16;
        float bv = (z == 0) ? bias[col] : 0.f;
        #pragma unroll
        for (int mt = 0; mt < 4; ++mt) {
            int rowb = bm + wm + mt * 16 + quad * 4;
            #pragma unroll
            for (int r = 0; r < 4; ++r)
                atomicAdd(&Out[(size_t)(rowb + r) * ldc + col],
                          acc[mt][nt][r] + bv);
        }
    }
}

// ---------------------------------------------------------------------------
// Direct GEMM for the small-ws fallback path (round-7 proven)
// ---------------------------------------------------------------------------
template <bool OUT_F32>
__global__ __launch_bounds__(256, 4) void gemm_direct(
    const short* __restrict__ A, int lda,
    const short* __restrict__ B, int ldb,
    void* __restrict__ Cv, int ldc,
    const float* __restrict__ bias, int K)
{
    __shared__ __align__(16) short As[128 * 64];
    __shared__ __align__(16) short Bs[128 * 64];

    f32x4 acc[4][4];
    #pragma unroll
    for (int i = 0; i < 4; ++i)
        #pragma unroll
        for (int j = 0; j < 4; ++j)
            acc[i][j] = (f32x4){0.f, 0.f, 0.f, 0.f};

    const int bm = blockIdx.y << 7;
    const int bn = blockIdx.x << 7;
    tile_core(A, lda, B, ldb, K, As, Bs, bm, bn, acc);

    const int tid  = threadIdx.x;
    const int wave = tid >> 6;
    const int lane = tid & 63;
    const int wm   = (wave >> 1) << 6;
    const int wn   = (wave & 1) << 6;
    const int l16  = lane & 15;
    const int quad = lane >> 4;

    if (OUT_F32) {
        float* C = (float*)Cv;
        #pragma unroll
        for (int nt = 0; nt < 4; ++nt) {
            int col = bn + wn + nt * 16 + l16;
            float bv = bias ? bias[col] : 0.f;
            #pragma unroll
            for (int mt = 0; mt < 4; ++mt) {
                int rowb = bm + wm + mt * 16 + quad * 4;
                #pragma unroll
                for (int r = 0; r < 4; ++r)
                    C[(size_t)(rowb + r) * ldc + col] = acc[mt][nt][r] + bv;
            }
        }
    } else {
        store_tile_bf16(acc, (short*)Cv, ldc, bm, bn);
    }
}

extern "C" void kernel_launch(void* const* d_in, const int* in_sizes, int n_in,
                              void* d_out, int out_size, void* d_ws, size_t ws_size,
                              hipStream_t stream) {
    const float* x    = (const float*)d_in[0];
    const float* Ur   = (const float*)d_in[1];
    const float* Ui   = (const float*)d_in[2];
    const float* S    = (const float*)d_in[3];
    const float* Vr   = (const float*)d_in[4];
    const float* Vi   = (const float*)d_in[5];
    const float* bias = (const float*)d_in[6];
    float* out = (float*)d_out;

    short* ws   = (short*)d_ws;
    short* xe   = ws;                                  // 1024*2048
    short* xo   = xe   + (size_t)1024 * 2048;          // 1024*2048
    short* B1f  = xo   + (size_t)1024 * 2048;          // 2048*2048
    short* Vcat = B1f  + (size_t)2048 * 2048;          // 2048*2048
    short* B2   = Vcat + (size_t)2048 * 2048;          // 1024*2048
    short* Ucat = B2   + (size_t)1024 * 2048;          // 4096*1024
    short* Xp   = Ucat + (size_t)4096 * 1024;          // 1024*2048
    short* T1   = Xp   + (size_t)1024 * 2048;          // 1024*2048
    short* Gm   = T1   + (size_t)1024 * 2048;          // 1024*1024
    short* Pp   = Gm   + (size_t)1024 * 1024;          // partials: 8.39M shorts

    const size_t need = (size_t)((char*)(Pp + (size_t)8388608) - (char*)d_ws);

    // x-side prep + out zero-init
    aux1<<<dim3(4096), 256, 0, stream>>>(x, xe, xo, B1f, out);

    if (ws_size >= need) {
        // g1 (folded s1, SK=4, Kpart=512, 512 blocks) + co-dispatched aux2
        gemm_s1f_aux<<<dim3(5632), 256, 0, stream>>>(
            xe, xo, B1f, Pp, Ur, Ui, S, Vr, Vi, Vcat, B2, Ucat);
        reduce_frag<false><<<dim3(1024), 256, 0, stream>>>(
            Pp, (size_t)2097152, 4, 16, Xp, 2048, nullptr);

        // T1 = Xp @ Vcat2^T (K=2048; SK=4, Kpart=512, 512 blocks)
        gemm_sk_frag<<<dim3(512), 256, 0, stream>>>(
            Xp, 2048, Vcat, 2048, Pp, (size_t)2097152, 512, 7, 4);
        reduce_frag<false><<<dim3(1024), 256, 0, stream>>>(
            Pp, (size_t)2097152, 4, 16, T1, 2048, nullptr);

        // G = T1 @ B2^T (1024x1024, K=2048; SK=8, Kpart=256, 512 blocks)
        gemm_sk_frag<<<dim3(512), 256, 0, stream>>>(
            T1, 2048, B2, 2048, Pp, (size_t)1048576, 256, 6, 3);
        reduce_frag<false><<<dim3(512), 256, 0, stream>>>(
            Pp, (size_t)1048576, 8, 8, Gm, 1024, nullptr);

        // out += G @ Ucat^T + bias (1024x4096, K=1024; SK=2, Kpart=512)
        gemm_sk_atomic<<<dim3(512), 256, 0, stream>>>(
            Gm, 1024, Ucat, 1024, 512, 8, 5, out, 4096, bias);
    } else {
        aux2_only<<<dim3(5120), 256, 0, stream>>>(
            Ur, Ui, S, Vr, Vi, Vcat, B2, Ucat);
        gemm_direct<false><<<dim3(8, 8), 256, 0, stream>>>(
            xe, 2048, B1f, 2048, Xp, 2048, nullptr, 2048);
        gemm_direct<false><<<dim3(8, 8), 256, 0, stream>>>(
            xo, 2048, B1f + (size_t)1024 * 2048, 2048, Xp + 1024, 2048,
            nullptr, 2048);
        gemm_direct<false><<<dim3(16, 8), 256, 0, stream>>>(
            Xp, 2048, Vcat, 2048, T1, 2048, nullptr, 2048);
        gemm_direct<false><<<dim3(8, 8), 256, 0, stream>>>(
            T1, 2048, B2, 2048, Gm, 1024, nullptr, 2048);
        gemm_direct<true><<<dim3(32, 8), 256, 0, stream>>>(
            Gm, 1024, Ucat, 1024, out, 4096, bias, 1024);
    }
}

// Round 5
// 185.233 us; speedup vs baseline: 1.0994x; 1.0994x over previous
//
#include <hip/hip_runtime.h>
#include <math.h>
#include <stdint.h>

#define PI2 6.28318530717958647692f

typedef __bf16 bf16x8 __attribute__((ext_vector_type(8)));
typedef float f32x4 __attribute__((ext_vector_type(4)));

typedef __attribute__((address_space(1))) const void gvoid_t;
typedef __attribute__((address_space(3))) void lvoid_t;

__device__ __forceinline__ void g2l16(const void* g, void* l) {
    __builtin_amdgcn_global_load_lds(
        reinterpret_cast<gvoid_t*>(reinterpret_cast<uintptr_t>(g)),
        reinterpret_cast<lvoid_t*>(reinterpret_cast<uintptr_t>(l)),
        16, 0, 0);
}

__device__ __forceinline__ short f2bf(float f) {
    unsigned u = __float_as_uint(f);
    u += 0x7FFFu + ((u >> 16) & 1u);          // round-to-nearest-even
    return (short)(u >> 16);
}

__device__ __forceinline__ unsigned pack2bf(float a, float b) {
    return (unsigned)(unsigned short)f2bf(a) |
           ((unsigned)(unsigned short)f2bf(b) << 16);
}

__device__ __forceinline__ float bflo(unsigned v) { return __uint_as_float(v << 16); }
__device__ __forceinline__ float bfhi(unsigned v) { return __uint_as_float(v & 0xFFFF0000u); }

// XCD-locality swizzle (grid must be a multiple of 8 -> bijective).
__device__ __forceinline__ int xcd_swizzle(int blk, int G) {
    return (blk & 7) * (G >> 3) + (blk >> 3);
}

// ---------------------------------------------------------------------------
// Fused aux kernel, 8 outputs per thread (fold region does 8+8), 8192 blocks.
// Regions (i8 = global element index, 8 shorts per thread):
//   [0,      2M):  xe/xo radix-2 fold of x (1024x2048 each, bf16)
//   [2M,     6M):  B1f folded DFT basis (2048x2048)
//   [6M,    10M):  Vcat2 (2048x2048), columns permuted to B1f channel order
//   [10M,   12M):  B2 (1024x2048), B2[p][k] = basis_p(k) * S[k]
//   [12M,   16M):  Ucat (4096x1024) = [Ur | Ui]
// ---------------------------------------------------------------------------
__global__ __launch_bounds__(256) void aux_all8(
    const float* __restrict__ x,
    const float* __restrict__ Ur, const float* __restrict__ Ui,
    const float* __restrict__ S,
    const float* __restrict__ Vr, const float* __restrict__ Vi,
    short* __restrict__ xe, short* __restrict__ xo,
    short* __restrict__ B1f, short* __restrict__ Vcat,
    short* __restrict__ B2, short* __restrict__ Ucat)
{
    unsigned i8 = (blockIdx.x * 256u + threadIdx.x) * 8u;
    if (i8 < 2097152u) {
        // radix-2 fold: xe = x[:, :2048] + x[:, 2048:], xo = difference
        unsigned i = i8;
        int r = i >> 11, j0 = i & 2047;
        const float* xr = x + (size_t)r * 4096 + j0;
        float4 a0 = ((const float4*)xr)[0], a1 = ((const float4*)xr)[1];
        float4 b0 = ((const float4*)(xr + 2048))[0],
               b1 = ((const float4*)(xr + 2048))[1];
        uint4 oe = {pack2bf(a0.x + b0.x, a0.y + b0.y),
                    pack2bf(a0.z + b0.z, a0.w + b0.w),
                    pack2bf(a1.x + b1.x, a1.y + b1.y),
                    pack2bf(a1.z + b1.z, a1.w + b1.w)};
        *(uint4*)(xe + i) = oe;
        uint4 oo = {pack2bf(a0.x - b0.x, a0.y - b0.y),
                    pack2bf(a0.z - b0.z, a0.w - b0.w),
                    pack2bf(a1.x - b1.x, a1.y - b1.y),
                    pack2bf(a1.z - b1.z, a1.w - b1.w)};
        *(uint4*)(xo + i) = oo;
    } else if (i8 < 6291456u) {
        unsigned i = i8 - 2097152u;
        int r = i >> 11, j0 = i & 2047;
        const float inv_n = 1.0f / 4096.0f;
        float v[8];
        if (r < 512) {
            if (r == 0) {
                #pragma unroll
                for (int u = 0; u < 8; ++u) v[u] = inv_n;
            } else {
                #pragma unroll
                for (int u = 0; u < 8; ++u) {
                    int t = (r * (j0 + u)) & 2047;
                    v[u] = 2.0f * inv_n * cosf((float)t * (PI2 / 2048.0f));
                }
            }
        } else if (r < 1024) {
            int m = r - 512;
            #pragma unroll
            for (int u = 0; u < 8; ++u) {
                int t = (m * (j0 + u)) & 2047;
                v[u] = -2.0f * inv_n * sinf((float)t * (PI2 / 2048.0f));
            }
        } else if (r < 1536) {
            int c = 2 * (r - 1024) + 1;
            #pragma unroll
            for (int u = 0; u < 8; ++u) {
                int t = (c * (j0 + u)) & 4095;
                v[u] = 2.0f * inv_n * cosf((float)t * (PI2 / 4096.0f));
            }
        } else {
            int m = 2 * (r - 1536) + 1;
            #pragma unroll
            for (int u = 0; u < 8; ++u) {
                int t = (m * (j0 + u)) & 4095;
                v[u] = -2.0f * inv_n * sinf((float)t * (PI2 / 4096.0f));
            }
        }
        uint4 o = {pack2bf(v[0], v[1]), pack2bf(v[2], v[3]),
                   pack2bf(v[4], v[5]), pack2bf(v[6], v[7])};
        *(uint4*)(B1f + i) = o;
    } else if (i8 < 10485760u) {
        // Vcat2 permuted copy: col cls 0:[Vr even] 1:[Vi even] 2:[Vr odd] 3:[Vi odd]
        unsigned i = i8 - 6291456u;
        int k = i >> 11, c0 = i & 2047;
        int cls = c0 >> 9, cc0 = c0 & 511;
        const float* src = ((cls & 1) ? Vi : Vr) + (size_t)k * 1024 + 2 * cc0;
        float4 q0 = ((const float4*)src)[0];
        float4 q1 = ((const float4*)src)[1];
        float4 q2 = ((const float4*)src)[2];
        float4 q3 = ((const float4*)src)[3];
        float v[8];
        if ((cls >> 1) == 0) {
            v[0] = q0.x; v[1] = q0.z; v[2] = q1.x; v[3] = q1.z;
            v[4] = q2.x; v[5] = q2.z; v[6] = q3.x; v[7] = q3.z;
        } else {
            v[0] = q0.y; v[1] = q0.w; v[2] = q1.y; v[3] = q1.w;
            v[4] = q2.y; v[5] = q2.w; v[6] = q3.y; v[7] = q3.w;
        }
        uint4 o = {pack2bf(v[0], v[1]), pack2bf(v[2], v[3]),
                   pack2bf(v[4], v[5]), pack2bf(v[6], v[7])};
        *(uint4*)(Vcat + i) = o;
    } else if (i8 < 12582912u) {
        // B2[p][k] = basis_p(k) * S[k], p-major (1024 x 2048)
        unsigned i = i8 - 10485760u;
        int p = i >> 11, k0 = i & 2047;
        float4 s0 = *(const float4*)(S + k0);
        float4 s1 = *(const float4*)(S + k0 + 4);
        float sv[8] = {s0.x, s0.y, s0.z, s0.w, s1.x, s1.y, s1.z, s1.w};
        const float inv_n = 1.0f / 2048.0f;
        float v[8];
        if (p == 0) {
            #pragma unroll
            for (int u = 0; u < 8; ++u) v[u] = inv_n * sv[u];
        } else if (p < 512) {
            #pragma unroll
            for (int u = 0; u < 8; ++u) {
                int t = (p * (k0 + u)) & 2047;
                v[u] = 2.0f * inv_n * cosf((float)t * (PI2 / 2048.0f)) * sv[u];
            }
        } else {
            int q = p - 512;
            #pragma unroll
            for (int u = 0; u < 8; ++u) {
                int t = (q * (k0 + u)) & 2047;
                v[u] = -2.0f * inv_n * sinf((float)t * (PI2 / 2048.0f)) * sv[u];
            }
        }
        uint4 o = {pack2bf(v[0], v[1]), pack2bf(v[2], v[3]),
                   pack2bf(v[4], v[5]), pack2bf(v[6], v[7])};
        *(uint4*)(B2 + i) = o;
    } else {
        unsigned i = i8 - 12582912u;
        int o_ = i >> 10, c = i & 1023;
        const float* src = (c < 512) ? (Ur + (size_t)o_ * 512 + c)
                                     : (Ui + (size_t)o_ * 512 + (c - 512));
        float4 a = ((const float4*)src)[0], b = ((const float4*)src)[1];
        uint4 o = {pack2bf(a.x, a.y), pack2bf(a.z, a.w),
                   pack2bf(b.x, b.y), pack2bf(b.z, b.w)};
        *(uint4*)(Ucat + i) = o;
    }
}

// ---------------------------------------------------------------------------
// 128x128 MFMA tile core, BK=64, XOR-swizzled LDS, NOW DOUBLE-BUFFERED:
// next K-tile's global_load_lds issues BEFORE the compute phase, so the
// compiler's vmcnt(0) drain at the single per-step __syncthreads() lands
// after ~400 cyc of MFMA instead of stalling cold. One barrier per K-step.
// LDS: 2 x 16 KB per operand = 64 KB/block -> 2 blocks/CU (grids are 512
// blocks = 2/CU anyway, so occupancy is unchanged).
// ---------------------------------------------------------------------------
__device__ __forceinline__ void tile_core(
    const short* __restrict__ A, int lda,
    const short* __restrict__ B, int ldb, int K,
    short* As, short* Bs, int bm, int bn, f32x4 (&acc)[4][4])
{
    const int tid  = threadIdx.x;
    const int wave = tid >> 6;
    const int lane = tid & 63;
    const int wm   = (wave >> 1) << 6;
    const int wn   = (wave & 1) << 6;
    const int l16  = lane & 15;
    const int quad = lane >> 4;
    const int rk   = l16 & 7;

    int aoff[4], boff[4], loff[4];
    #pragma unroll
    for (int p = 0; p < 4; ++p) {
        int L   = p * 256 + wave * 64 + lane;
        int row = L >> 3;
        int swz = (L & 7) ^ (row & 7);
        aoff[p] = (bm + row) * lda + swz * 8;
        boff[p] = (bn + row) * ldb + swz * 8;
        loff[p] = L * 8;
    }

    // prologue: stage K-tile 0 into buffer 0
    #pragma unroll
    for (int p = 0; p < 4; ++p) g2l16(A + aoff[p], As + loff[p]);
    #pragma unroll
    for (int p = 0; p < 4; ++p) g2l16(B + boff[p], Bs + loff[p]);
    __syncthreads();

    int cur = 0;
    for (int k0 = 0; k0 < K; k0 += 64) {
        const int nxt = cur ^ 1;
        if (k0 + 64 < K) {
            // issue next-tile loads FIRST; they retire during the MFMA phase
            #pragma unroll
            for (int p = 0; p < 4; ++p)
                g2l16(A + aoff[p] + k0 + 64, As + nxt * 8192 + loff[p]);
            #pragma unroll
            for (int p = 0; p < 4; ++p)
                g2l16(B + boff[p] + k0 + 64, Bs + nxt * 8192 + loff[p]);
        }

        const short* Asc = As + cur * 8192;
        const short* Bsc = Bs + cur * 8192;
        #pragma unroll
        for (int h = 0; h < 2; ++h) {
            const int cs8 = ((((h << 2) | quad) ^ rk) << 3);
            bf16x8 b[4];
            #pragma unroll
            for (int nt = 0; nt < 4; ++nt)
                b[nt] = *(const bf16x8*)(Bsc + (wn + nt * 16 + l16) * 64 + cs8);
            #pragma unroll
            for (int mt = 0; mt < 4; ++mt) {
                bf16x8 a = *(const bf16x8*)(Asc + (wm + mt * 16 + l16) * 64 + cs8);
                #pragma unroll
                for (int nt = 0; nt < 4; ++nt)
                    acc[mt][nt] = __builtin_amdgcn_mfma_f32_16x16x32_bf16(
                        a, b[nt], acc[mt][nt], 0, 0, 0);
            }
        }
        __syncthreads();   // drains (already-retired) next-tile loads + syncs
        cur = nxt;
    }
}

__device__ __forceinline__ void store_tile_bf16(
    f32x4 (&acc)[4][4], short* __restrict__ C, int ldc, int bm, int bn)
{
    const int tid  = threadIdx.x;
    const int wave = tid >> 6;
    const int lane = tid & 63;
    const int wm   = (wave >> 1) << 6;
    const int wn   = (wave & 1) << 6;
    const int l16  = lane & 15;
    const int quad = lane >> 4;
    #pragma unroll
    for (int nt = 0; nt < 4; ++nt) {
        int col = bn + wn + nt * 16 + l16;
        #pragma unroll
        for (int mt = 0; mt < 4; ++mt) {
            int rowb = bm + wm + mt * 16 + quad * 4;
            #pragma unroll
            for (int r = 0; r < 4; ++r)
                C[(size_t)(rowb + r) * ldc + col] = f2bf(acc[mt][nt][r]);
        }
    }
}

// Fragment-layout store: 8 coalesced uint4 per thread (round-7 proven).
__device__ __forceinline__ void store_frag(
    f32x4 (&acc)[4][4], short* __restrict__ planeTile)
{
    uint4* p = (uint4*)planeTile;
    const int tid = threadIdx.x;
    #pragma unroll
    for (int c = 0; c < 8; ++c) {
        int nt = c >> 1, mt0 = (c & 1) * 2;
        uint4 o = {pack2bf(acc[mt0][nt][0],     acc[mt0][nt][1]),
                   pack2bf(acc[mt0][nt][2],     acc[mt0][nt][3]),
                   pack2bf(acc[mt0 + 1][nt][0], acc[mt0 + 1][nt][1]),
                   pack2bf(acc[mt0 + 1][nt][2], acc[mt0 + 1][nt][3])};
        p[c * 256 + tid] = o;
    }
}

// Reduce one fragment chunk (tile, c) across SK planes -> row-major output.
template <bool OUT_F32>
__device__ __forceinline__ void reduce_unit(
    const short* __restrict__ P, size_t planeU4, int SK,
    int tile, int c, int tilesX, void* __restrict__ Out, int ldc,
    const float* __restrict__ bias)
{
    const int bm = (tile / tilesX) << 7;
    const int bn = (tile % tilesX) << 7;
    const int tid  = threadIdx.x;
    const int wave = tid >> 6;
    const int lane = tid & 63;
    const int wm   = (wave >> 1) << 6;
    const int wn   = (wave & 1) << 6;
    const int l16  = lane & 15;
    const int quad = lane >> 4;
    const int nt   = c >> 1, mt0 = (c & 1) * 2;

    const uint4* P4 = (const uint4*)P;
    const size_t base = (size_t)tile * 2048 + (size_t)c * 256 + tid;
    float f[8] = {0, 0, 0, 0, 0, 0, 0, 0};
    for (int z = 0; z < SK; ++z) {
        uint4 v = P4[(size_t)z * planeU4 + base];
        f[0] += bflo(v.x); f[1] += bfhi(v.x);
        f[2] += bflo(v.y); f[3] += bfhi(v.y);
        f[4] += bflo(v.z); f[5] += bfhi(v.z);
        f[6] += bflo(v.w); f[7] += bfhi(v.w);
    }
    const int col = bn + wn + nt * 16 + l16;
    float bv = 0.f;
    if (OUT_F32) bv = bias[col];
    #pragma unroll
    for (int j = 0; j < 8; ++j) {
        int mt  = mt0 + (j >> 2);
        int row = bm + wm + mt * 16 + quad * 4 + (j & 3);
        if (OUT_F32)
            ((float*)Out)[(size_t)row * ldc + col] = f[j] + bv;
        else
            ((short*)Out)[(size_t)row * ldc + col] = f2bf(f[j]);
    }
}

// ---------------------------------------------------------------------------
// Stage-1 folded GEMM: Xp[:, :1024] = xe @ B1f[:1024]^T,
//                      Xp[:, 1024:] = xo @ B1f[1024:]^T.
// SK=4, Kpart=512, 8x16 logical tile grid -> 512 blocks, frag partials.
// ---------------------------------------------------------------------------
__global__ __launch_bounds__(256, 2) void gemm_s1f(
    const short* __restrict__ xe, const short* __restrict__ xo,
    const short* __restrict__ B1f, short* __restrict__ P)
{
    __shared__ __align__(16) short As[2 * 128 * 64];
    __shared__ __align__(16) short Bs[2 * 128 * 64];

    f32x4 acc[4][4];
    #pragma unroll
    for (int i = 0; i < 4; ++i)
        #pragma unroll
        for (int j = 0; j < 4; ++j)
            acc[i][j] = (f32x4){0.f, 0.f, 0.f, 0.f};

    const int u    = xcd_swizzle((int)blockIdx.x, (int)gridDim.x);
    const int z    = u >> 7;          // SK = 4
    const int tile = u & 127;         // 8 x 16 tiles
    const int tx   = tile & 15, ty = tile >> 4;
    const bool odd = (tx & 8) != 0;
    const short* A = (odd ? xo : xe) + (size_t)z * 512;
    const short* B = B1f + (odd ? (size_t)1024 * 2048 : 0) + (size_t)z * 512;
    const int bm   = ty << 7;
    const int bn   = (tx & 7) << 7;

    tile_core(A, 2048, B, 2048, 512, As, Bs, bm, bn, acc);
    store_frag(acc, P + (size_t)z * 2097152 + (size_t)tile * 16384);
}

// ---------------------------------------------------------------------------
// Split-K GEMM into fragment-layout bf16 partial planes, 1-D grid,
// XCD-swizzled. tileShift: log2(tiles per plane); tilesXShift: log2(tilesX).
// ---------------------------------------------------------------------------
__global__ __launch_bounds__(256, 2) void gemm_sk_frag(
    const short* __restrict__ A, int lda,
    const short* __restrict__ B, int ldb,
    short* __restrict__ P, size_t planeShorts, int Kpart,
    int tileShift, int tilesXShift)
{
    __shared__ __align__(16) short As[2 * 128 * 64];
    __shared__ __align__(16) short Bs[2 * 128 * 64];

    f32x4 acc[4][4];
    #pragma unroll
    for (int i = 0; i < 4; ++i)
        #pragma unroll
        for (int j = 0; j < 4; ++j)
            acc[i][j] = (f32x4){0.f, 0.f, 0.f, 0.f};

    const int u    = xcd_swizzle((int)blockIdx.x, (int)gridDim.x);
    const int z    = u >> tileShift;
    const int tile = u & ((1 << tileShift) - 1);
    const int bm   = (tile >> tilesXShift) << 7;
    const int bn   = (tile & ((1 << tilesXShift) - 1)) << 7;

    tile_core(A + (size_t)z * Kpart, lda, B + (size_t)z * Kpart, ldb, Kpart,
              As, Bs, bm, bn, acc);
    store_frag(acc, P + (size_t)z * planeShorts + (size_t)tile * 16384);
}

template <bool OUT_F32>
__global__ __launch_bounds__(256) void reduce_frag(
    const short* __restrict__ P, size_t planeShorts, int SK,
    int tilesX, void* __restrict__ Out, int ldc,
    const float* __restrict__ bias)
{
    reduce_unit<OUT_F32>(P, planeShorts >> 3, SK,
                         (int)(blockIdx.x >> 3), (int)(blockIdx.x & 7),
                         tilesX, Out, ldc, bias);
}

// ---------------------------------------------------------------------------
// Direct GEMM for the small-ws fallback path (round-7 proven)
// ---------------------------------------------------------------------------
template <bool OUT_F32>
__global__ __launch_bounds__(256, 2) void gemm_direct(
    const short* __restrict__ A, int lda,
    const short* __restrict__ B, int ldb,
    void* __restrict__ Cv, int ldc,
    const float* __restrict__ bias, int K)
{
    __shared__ __align__(16) short As[2 * 128 * 64];
    __shared__ __align__(16) short Bs[2 * 128 * 64];

    f32x4 acc[4][4];
    #pragma unroll
    for (int i = 0; i < 4; ++i)
        #pragma unroll
        for (int j = 0; j < 4; ++j)
            acc[i][j] = (f32x4){0.f, 0.f, 0.f, 0.f};

    const int bm = blockIdx.y << 7;
    const int bn = blockIdx.x << 7;
    tile_core(A, lda, B, ldb, K, As, Bs, bm, bn, acc);

    const int tid  = threadIdx.x;
    const int wave = tid >> 6;
    const int lane = tid & 63;
    const int wm   = (wave >> 1) << 6;
    const int wn   = (wave & 1) << 6;
    const int l16  = lane & 15;
    const int quad = lane >> 4;

    if (OUT_F32) {
        float* C = (float*)Cv;
        #pragma unroll
        for (int nt = 0; nt < 4; ++nt) {
            int col = bn + wn + nt * 16 + l16;
            float bv = bias ? bias[col] : 0.f;
            #pragma unroll
            for (int mt = 0; mt < 4; ++mt) {
                int rowb = bm + wm + mt * 16 + quad * 4;
                #pragma unroll
                for (int r = 0; r < 4; ++r)
                    C[(size_t)(rowb + r) * ldc + col] = acc[mt][nt][r] + bv;
            }
        }
    } else {
        store_tile_bf16(acc, (short*)Cv, ldc, bm, bn);
    }
}

extern "C" void kernel_launch(void* const* d_in, const int* in_sizes, int n_in,
                              void* d_out, int out_size, void* d_ws, size_t ws_size,
                              hipStream_t stream) {
    const float* x    = (const float*)d_in[0];
    const float* Ur   = (const float*)d_in[1];
    const float* Ui   = (const float*)d_in[2];
    const float* S    = (const float*)d_in[3];
    const float* Vr   = (const float*)d_in[4];
    const float* Vi   = (const float*)d_in[5];
    const float* bias = (const float*)d_in[6];
    float* out = (float*)d_out;

    short* ws   = (short*)d_ws;
    short* xe   = ws;                                  // 1024*2048
    short* xo   = xe   + (size_t)1024 * 2048;          // 1024*2048
    short* B1f  = xo   + (size_t)1024 * 2048;          // 2048*2048
    short* Vcat = B1f  + (size_t)2048 * 2048;          // 2048*2048
    short* B2   = Vcat + (size_t)2048 * 2048;          // 1024*2048
    short* Ucat = B2   + (size_t)1024 * 2048;          // 4096*1024
    short* Xp   = Ucat + (size_t)4096 * 1024;          // 1024*2048
    short* T1   = Xp   + (size_t)1024 * 2048;          // 1024*2048
    short* Gm   = T1   + (size_t)1024 * 2048;          // 1024*1024
    short* Pp   = Gm   + (size_t)1024 * 1024;          // partials: 8.39M shorts

    const size_t need = (size_t)((char*)(Pp + (size_t)8388608) - (char*)d_ws);

    aux_all8<<<dim3(8192), 256, 0, stream>>>(
        x, Ur, Ui, S, Vr, Vi, xe, xo, B1f, Vcat, B2, Ucat);

    if (ws_size >= need) {
        // s1 (folded, SK=4, Kpart=512, 512 blocks) -> Xp (1024x2048)
        gemm_s1f<<<dim3(512), 256, 0, stream>>>(xe, xo, B1f, Pp);
        reduce_frag<false><<<dim3(1024), 256, 0, stream>>>(
            Pp, (size_t)2097152, 4, 16, Xp, 2048, nullptr);

        // T1 = Xp @ Vcat2^T (K=2048; SK=4, Kpart=512, 512 blocks)
        gemm_sk_frag<<<dim3(512), 256, 0, stream>>>(
            Xp, 2048, Vcat, 2048, Pp, (size_t)2097152, 512, 7, 4);
        reduce_frag<false><<<dim3(1024), 256, 0, stream>>>(
            Pp, (size_t)2097152, 4, 16, T1, 2048, nullptr);

        // G = T1 @ B2^T (1024x1024, K=2048; SK=8, Kpart=256, 512 blocks)
        gemm_sk_frag<<<dim3(512), 256, 0, stream>>>(
            T1, 2048, B2, 2048, Pp, (size_t)1048576, 256, 6, 3);
        reduce_frag<false><<<dim3(512), 256, 0, stream>>>(
            Pp, (size_t)1048576, 8, 8, Gm, 1024, nullptr);

        // out = T1' @ Ucat^T + bias (1024x4096, K=1024; SK=2, Kpart=512)
        gemm_sk_frag<<<dim3(512), 256, 0, stream>>>(
            Gm, 1024, Ucat, 1024, Pp, (size_t)4194304, 512, 8, 5);
        reduce_frag<true><<<dim3(2048), 256, 0, stream>>>(
            Pp, (size_t)4194304, 2, 32, out, 4096, bias);
    } else {
        gemm_direct<false><<<dim3(8, 8), 256, 0, stream>>>(
            xe, 2048, B1f, 2048, Xp, 2048, nullptr, 2048);
        gemm_direct<false><<<dim3(8, 8), 256, 0, stream>>>(
            xo, 2048, B1f + (size_t)1024 * 2048, 2048, Xp + 1024, 2048,
            nullptr, 2048);
        gemm_direct<false><<<dim3(16, 8), 256, 0, stream>>>(
            Xp, 2048, Vcat, 2048, T1, 2048, nullptr, 2048);
        gemm_direct<false><<<dim3(8, 8), 256, 0, stream>>>(
            T1, 2048, B2, 2048, Gm, 1024, nullptr, 2048);
        gemm_direct<true><<<dim3(32, 8), 256, 0, stream>>>(
            Gm, 1024, Ucat, 1024, out, 4096, bias, 1024);
    }
}